// Round 1
// baseline (382.364 us; speedup 1.0000x reference)
//
#include <hip/hip_runtime.h>
#include <hip/hip_bf16.h>
#include <stdint.h>

#define D_IN    512
#define NTOT    32896
#define BATCH   4096
#define NWG_GEMM 8224   // 32 m-tiles * 257 n-tiles
#define XCD_CHUNK 1028  // NWG_GEMM / 8

typedef __attribute__((ext_vector_type(8))) short short8;
typedef __attribute__((ext_vector_type(4))) float f32x4;

__device__ __forceinline__ unsigned short f2bf(float f) {
    union { float f; uint32_t u; } v; v.f = f;
    // round-to-nearest-even fp32 -> bf16
    return (unsigned short)((v.u + 0x7fffu + ((v.u >> 16) & 1u)) >> 16);
}

// x [BATCH][D_IN] fp32 -> bf16, same layout (K contiguous)
__global__ __launch_bounds__(256) void convx_kernel(const float* __restrict__ x,
                                                    unsigned short* __restrict__ xb) {
    int tid = blockIdx.x * 256 + threadIdx.x;   // 262144 threads, 8 elems each
    const float4* xv = (const float4*)x;
    float4 a = xv[2 * tid];
    float4 c = xv[2 * tid + 1];
    short8 o;
    o[0] = (short)f2bf(a.x); o[1] = (short)f2bf(a.y);
    o[2] = (short)f2bf(a.z); o[3] = (short)f2bf(a.w);
    o[4] = (short)f2bf(c.x); o[5] = (short)f2bf(c.y);
    o[6] = (short)f2bf(c.z); o[7] = (short)f2bf(c.w);
    ((short8*)xb)[tid] = o;
}

// W [D_IN][NTOT] fp32 -> k-packed bf16: Wp[g][n][r] = W[g*8+r][n], g in [0,64)
__global__ __launch_bounds__(256) void convw_kernel(const float* __restrict__ W,
                                                    unsigned short* __restrict__ wp) {
    int tid = blockIdx.x * 256 + threadIdx.x;   // 64*32896 threads
    int g = tid / NTOT;
    int n = tid - g * NTOT;
    const float* src = W + (size_t)g * 8u * NTOT + n;
    short8 o;
#pragma unroll
    for (int r = 0; r < 8; ++r) o[r] = (short)f2bf(src[(size_t)r * NTOT]);
    ((short8*)wp)[(size_t)g * NTOT + n] = o;
}

__device__ __forceinline__ void gload16(const void* g, void* l) {
    __builtin_amdgcn_global_load_lds(
        (const __attribute__((address_space(1))) void*)g,
        (__attribute__((address_space(3))) void*)l, 16, 0, 0);
}

// C[M][N] = Ab * Wp + bias, bf16 inputs, fp32 accumulate/output.
// 128x128 tile, BK=32, 4 waves in 2x2, each wave 64x64 = 4x4 mfma 16x16x32 frags.
__global__ __launch_bounds__(256, 2) void gemm_kernel(
        const unsigned short* __restrict__ Ab,   // [BATCH][D_IN] bf16
        const unsigned short* __restrict__ Bp,   // [D_IN/8][NTOT][8] bf16 (k-packed)
        const float* __restrict__ bias,          // [NTOT] fp32
        float* __restrict__ C) {                 // [BATCH][NTOT] fp32
    // k-packed LDS: sA[g][row] = 8 bf16 (k = k0+g*8 .. +8) of A row; sB[g][n] likewise.
    __shared__ short8 sA[4][128];   // 8 KB
    __shared__ short8 sB[4][128];   // 8 KB

    const int bid = (int)blockIdx.x;
    // chunked XCD swizzle (bijective: 8224 % 8 == 0): blocks on one XCD get a
    // contiguous wg range -> 32 consecutive wg share one 128-col W panel.
    const int wg  = (bid & 7) * XCD_CHUNK + (bid >> 3);
    const int mt  = wg & 31;        // 32 m-tiles
    const int nt  = wg >> 5;        // 257 n-tiles
    const int brow = mt * 128;
    const int bcol = nt * 128;

    const int tid  = (int)threadIdx.x;
    const int lane = tid & 63;
    const int w    = tid >> 6;      // wave 0..3
    const int wr   = w >> 1;        // wave row (0,1)
    const int wc   = w & 1;         // wave col (0,1)

    f32x4 acc[4][4] = {};

    // Staging: wave w owns k-group g=w of both tiles, halves h=0,1.
    // LDS dest is wave-uniform base; HW scatters lane i at base + i*16.
    const unsigned short* gA0 = Ab + (size_t)(brow + 0 * 64 + lane) * D_IN + w * 8;
    const unsigned short* gA1 = Ab + (size_t)(brow + 1 * 64 + lane) * D_IN + w * 8;
    const unsigned short* gB0 = Bp + ((size_t)w * NTOT + bcol + 0 * 64 + lane) * 8;
    const unsigned short* gB1 = Bp + ((size_t)w * NTOT + bcol + 1 * 64 + lane) * 8;
    void* lA0 = (void*)&sA[w][0];
    void* lA1 = (void*)&sA[w][64];
    void* lB0 = (void*)&sB[w][0];
    void* lB1 = (void*)&sB[w][64];

    const int g  = lane >> 4;       // k-group of this lane's fragment
    const int fr = lane & 15;       // row (A) / col (B) within fragment

    for (int it = 0; it < 16; ++it) {
        gload16(gA0, lA0);
        gload16(gA1, lA1);
        gload16(gB0, lB0);
        gload16(gB1, lB1);
        gA0 += 32; gA1 += 32;                       // advance k by 32 bf16
        gB0 += (size_t)4 * NTOT * 8;                // advance 4 k-groups
        gB1 += (size_t)4 * NTOT * 8;
        __syncthreads();   // compiler drains vmcnt before s_barrier

        short8 aF[4], bF[4];
#pragma unroll
        for (int m = 0; m < 4; ++m) aF[m] = sA[g][wr * 64 + m * 16 + fr];
#pragma unroll
        for (int n = 0; n < 4; ++n) bF[n] = sB[g][wc * 64 + n * 16 + fr];
#pragma unroll
        for (int m = 0; m < 4; ++m)
#pragma unroll
            for (int n = 0; n < 4; ++n)
                acc[m][n] = __builtin_amdgcn_mfma_f32_16x16x32_bf16(
                    aF[m], bF[n], acc[m][n], 0, 0, 0);
        __syncthreads();   // protect LDS from next iter's staging
    }

    // Epilogue: C/D layout col = lane&15, row = (lane>>4)*4 + reg (m89-verified).
    const int rowb = brow + wr * 64 + (lane >> 4) * 4;
    const int colb = bcol + wc * 64 + fr;
#pragma unroll
    for (int n = 0; n < 4; ++n) {
        const int gcol = colb + n * 16;
        const float bv = bias[gcol];
#pragma unroll
        for (int m = 0; m < 4; ++m) {
            float* dst = C + (size_t)(rowb + m * 16) * NTOT + gcol;
#pragma unroll
            for (int q = 0; q < 4; ++q)
                dst[(size_t)q * NTOT] = acc[m][n][q] + bv;
        }
    }
}

extern "C" void kernel_launch(void* const* d_in, const int* in_sizes, int n_in,
                              void* d_out, int out_size, void* d_ws, size_t ws_size,
                              hipStream_t stream) {
    const float* x = (const float*)d_in[0];
    const float* W = (const float*)d_in[1];
    const float* b = (const float*)d_in[2];
    float* out = (float*)d_out;

    unsigned short* xb = (unsigned short*)d_ws;               // 4 MB
    unsigned short* wp = xb + (size_t)BATCH * D_IN;           // +33.7 MB

    convx_kernel<<<(BATCH * D_IN / 8) / 256, 256, 0, stream>>>(x, xb);
    convw_kernel<<<((D_IN / 8) * NTOT) / 256, 256, 0, stream>>>(W, wp);
    gemm_kernel<<<NWG_GEMM, 256, 0, stream>>>(xb, wp, b, out);
}

// Round 3
// 269.594 us; speedup vs baseline: 1.4183x; 1.4183x over previous
//
#include <hip/hip_runtime.h>
#include <hip/hip_bf16.h>
#include <stdint.h>

#define D_IN    512
#define NTOT    32896
#define BATCH   4096
#define NWG_GEMM 8224   // 32 m-tiles * 257 n-tiles
#define XCD_CHUNK 1028  // NWG_GEMM / 8

typedef __attribute__((ext_vector_type(8))) short short8;
typedef __attribute__((ext_vector_type(4))) float f32x4;

__device__ __forceinline__ unsigned short f2bf(float f) {
    union { float f; uint32_t u; } v; v.f = f;
    // round-to-nearest-even fp32 -> bf16
    return (unsigned short)((v.u + 0x7fffu + ((v.u >> 16) & 1u)) >> 16);
}

// x [BATCH][D_IN] fp32 -> bf16, same layout (K contiguous)
__global__ __launch_bounds__(256) void convx_kernel(const float* __restrict__ x,
                                                    unsigned short* __restrict__ xb) {
    int tid = blockIdx.x * 256 + threadIdx.x;   // 262144 threads, 8 elems each
    const f32x4* xv = (const f32x4*)x;
    f32x4 a = __builtin_nontemporal_load(xv + 2 * tid);
    f32x4 c = __builtin_nontemporal_load(xv + 2 * tid + 1);
    short8 o;
    o[0] = (short)f2bf(a[0]); o[1] = (short)f2bf(a[1]);
    o[2] = (short)f2bf(a[2]); o[3] = (short)f2bf(a[3]);
    o[4] = (short)f2bf(c[0]); o[5] = (short)f2bf(c[1]);
    o[6] = (short)f2bf(c[2]); o[7] = (short)f2bf(c[3]);
    ((short8*)xb)[tid] = o;
}

// W [D_IN][NTOT] fp32 -> k-packed bf16: Wp[g][n][r] = W[g*8+r][n], g in [0,64)
__global__ __launch_bounds__(256) void convw_kernel(const float* __restrict__ W,
                                                    unsigned short* __restrict__ wp) {
    int tid = blockIdx.x * 256 + threadIdx.x;   // 64*32896 threads
    int g = tid / NTOT;
    int n = tid - g * NTOT;
    const float* src = W + (size_t)g * 8u * NTOT + n;
    short8 o;
#pragma unroll
    for (int r = 0; r < 8; ++r) o[r] = (short)f2bf(__builtin_nontemporal_load(src + (size_t)r * NTOT));
    ((short8*)wp)[(size_t)g * NTOT + n] = o;
}

__device__ __forceinline__ void gload16(const void* g, void* l) {
    __builtin_amdgcn_global_load_lds(
        (const __attribute__((address_space(1))) void*)g,
        (__attribute__((address_space(3))) void*)l, 16, 0, 0);
}

// C[M][N] = Ab * Wp + bias, bf16 inputs, fp32 accumulate/output.
// 128x128 tile, BK=32, double-buffered LDS 2-phase pipeline.
// 4 waves in 2x2, each wave 64x64 = 4x4 mfma 16x16x32 frags.
__global__ __launch_bounds__(256, 3) void gemm_kernel(
        const unsigned short* __restrict__ Ab,   // [BATCH][D_IN] bf16
        const unsigned short* __restrict__ Bp,   // [D_IN/8][NTOT][8] bf16 (k-packed)
        const float* __restrict__ bias,          // [NTOT] fp32
        float* __restrict__ C) {                 // [BATCH][NTOT] fp32
    // k-packed LDS: sA[buf][g][row] = 8 bf16 (k-group g) of A row; sB likewise.
    __shared__ short8 sA[2][4][128];   // 16 KB
    __shared__ short8 sB[2][4][128];   // 16 KB

    const int bid = (int)blockIdx.x;
    // chunked XCD swizzle (bijective: 8224 % 8 == 0): one XCD's blocks span a
    // contiguous wg range; mt-fastest order keeps one 128-col W panel L2-hot
    // across all 32 m-tiles.
    const int wg  = (bid & 7) * XCD_CHUNK + (bid >> 3);
    const int mt  = wg & 31;        // 32 m-tiles
    const int nt  = wg >> 5;        // 257 n-tiles
    const int brow = mt * 128;
    const int bcol = nt * 128;

    const int tid  = (int)threadIdx.x;
    const int lane = tid & 63;
    const int w    = tid >> 6;      // wave 0..3
    const int wr   = w >> 1;        // wave row (0,1)
    const int wc   = w & 1;         // wave col (0,1)

    f32x4 acc[4][4] = {};

    // Staging: wave w owns k-group g=w of both tiles, halves h=0,1.
    // global_load_lds: LDS dest = wave-uniform base + lane*16 (linear).
    const unsigned short* gA0 = Ab + (size_t)(brow + lane) * D_IN + w * 8;
    const unsigned short* gA1 = Ab + (size_t)(brow + 64 + lane) * D_IN + w * 8;
    const unsigned short* gB0 = Bp + ((size_t)w * NTOT + bcol + lane) * 8;
    const unsigned short* gB1 = Bp + ((size_t)w * NTOT + bcol + 64 + lane) * 8;
    const size_t bstep = (size_t)4 * NTOT * 8;   // advance 4 k-groups

    const int g  = lane >> 4;       // k-group of this lane's fragment
    const int fr = lane & 15;       // row (A) / col (B) within fragment

    // --- prologue: stage K-tile 0 into buffer 0 ---
    gload16(gA0, (void*)&sA[0][w][0]);
    gload16(gA1, (void*)&sA[0][w][64]);
    gload16(gB0, (void*)&sB[0][w][0]);
    gload16(gB1, (void*)&sB[0][w][64]);
    gA0 += 32; gA1 += 32; gB0 += bstep; gB1 += bstep;
    __syncthreads();                 // drains vmcnt(0): tile 0 resident

    int cur = 0;
    for (int it = 0; it < 16; ++it) {
        // stage NEXT K-tile into the other buffer; latency overlaps this
        // tile's ds_read + MFMA (single vmcnt-drain at the barrier below).
        if (it < 15) {
            const int nxt = cur ^ 1;
            gload16(gA0, (void*)&sA[nxt][w][0]);
            gload16(gA1, (void*)&sA[nxt][w][64]);
            gload16(gB0, (void*)&sB[nxt][w][0]);
            gload16(gB1, (void*)&sB[nxt][w][64]);
            gA0 += 32; gA1 += 32; gB0 += bstep; gB1 += bstep;
        }

        short8 aF[4], bF[4];
#pragma unroll
        for (int m = 0; m < 4; ++m) aF[m] = sA[cur][g][wr * 64 + m * 16 + fr];
#pragma unroll
        for (int n = 0; n < 4; ++n) bF[n] = sB[cur][g][wc * 64 + n * 16 + fr];
#pragma unroll
        for (int m = 0; m < 4; ++m)
#pragma unroll
            for (int n = 0; n < 4; ++n)
                acc[m][n] = __builtin_amdgcn_mfma_f32_16x16x32_bf16(
                    aF[m], bF[n], acc[m][n], 0, 0, 0);

        __syncthreads();             // next tile staged + LDS safe to reuse
        cur ^= 1;
    }

    // Epilogue: C/D layout col = lane&15, row = (lane>>4)*4 + reg (m89-verified).
    // Nontemporal stores (output is write-once) kill TCC write-allocate fetch;
    // n-innermost order makes 4 consecutive stores cover contiguous 256 B/row.
    const int rowb = brow + wr * 64 + (lane >> 4) * 4;
    const int colb = bcol + wc * 64 + fr;
    float bv[4];
#pragma unroll
    for (int n = 0; n < 4; ++n) bv[n] = bias[colb + n * 16];
#pragma unroll
    for (int m = 0; m < 4; ++m) {
#pragma unroll
        for (int q = 0; q < 4; ++q) {
            float* rowp = C + (size_t)(rowb + m * 16 + q) * NTOT + colb;
#pragma unroll
            for (int n = 0; n < 4; ++n)
                __builtin_nontemporal_store(acc[m][n][q] + bv[n], rowp + n * 16);
        }
    }
}

extern "C" void kernel_launch(void* const* d_in, const int* in_sizes, int n_in,
                              void* d_out, int out_size, void* d_ws, size_t ws_size,
                              hipStream_t stream) {
    const float* x = (const float*)d_in[0];
    const float* W = (const float*)d_in[1];
    const float* b = (const float*)d_in[2];
    float* out = (float*)d_out;

    unsigned short* xb = (unsigned short*)d_ws;               // 4 MB
    unsigned short* wp = xb + (size_t)BATCH * D_IN;           // +33.7 MB

    convx_kernel<<<(BATCH * D_IN / 8) / 256, 256, 0, stream>>>(x, xb);
    convw_kernel<<<((D_IN / 8) * NTOT) / 256, 256, 0, stream>>>(W, wp);
    gemm_kernel<<<NWG_GEMM, 256, 0, stream>>>(xb, wp, b, out);
}